// Round 8
// baseline (37827.707 us; speedup 1.0000x reference)
//
#include <hip/hip_runtime.h>
#include <math.h>

#define DM    1024
#define NH    16
#define DKH   64
#define NL    4
#define DFFN  4096
#define BB    4
#define TT    1024
#define NSTEP 24
#define BT    (BB*TT)      // 4096 encoder rows
#define MD    (BB*NSTEP)   // 96 decoder rows max (packed: row = i*4 + b)
#define CSPLIT 8
#define CKEYS  (TT/CSPLIT) // 128 keys per cross-attn split
#define NB    384          // persistent decoder grid (<= 512 capacity, margin for safety)
#define NROW  96
#define PSTRIDE ((size_t)NROW*DM)      // FFN2 partial stride (f32)

typedef __attribute__((ext_vector_type(8))) short s16x8;
typedef __attribute__((ext_vector_type(4))) short s16x4;
typedef __attribute__((ext_vector_type(4))) float f32x4;

__device__ inline short f2b(float f){
  unsigned u = __float_as_uint(f);
  u += 0x7fffu + ((u>>16)&1u);          // round-to-nearest-even
  return (short)(u>>16);
}
__device__ inline float b2f(short h){
  return __uint_as_float(((unsigned)(unsigned short)h)<<16);
}

__device__ inline float wave_sum(float v){
  #pragma unroll
  for (int off=1; off<64; off<<=1) v += __shfl_xor(v, off, 64);
  return v;
}

// ---------------- f32 -> (hi,lo) bf16 split ----------------
__global__ __launch_bounds__(256)
void split_kernel(const float* __restrict__ X, short* __restrict__ Hi,
                  short* __restrict__ Lo, int n8)
{
  const size_t i = (size_t)blockIdx.x*256 + threadIdx.x;
  if (i >= (size_t)n8) return;
  const float4 v0 = *(const float4*)(X + i*8);
  const float4 v1 = *(const float4*)(X + i*8 + 4);
  const float f[8] = {v0.x,v0.y,v0.z,v0.w,v1.x,v1.y,v1.z,v1.w};
  s16x8 hv, lv;
  #pragma unroll
  for (int e=0;e<8;e++){
    const short h = f2b(f[e]);
    hv[e] = h;
    lv[e] = f2b(f[e] - b2f(h));
  }
  *(s16x8*)(Hi + i*8) = hv;
  *(s16x8*)(Lo + i*8) = lv;
}

__global__ void zero_kernel(float* __restrict__ p, int n) {
  int i = blockIdx.x*256 + threadIdx.x;
  if (i < n) p[i] = 0.f;
}

// h[row] + pe[row%TT] -> split bf16 (encoder)
__global__ __launch_bounds__(256)
void add_pe_split(const float* __restrict__ h, short* __restrict__ Hi,
                  short* __restrict__ Lo)
{
  const int row = blockIdx.x;
  const int pos = row & (TT-1);
  const int d = threadIdx.x*4;
  const float4 a = *(const float4*)(h + (size_t)row*DM + d);
  const float c1 = -9.210340371976184f / 1024.0f;
  const float e0 = expf((float)d * c1);
  const float e1 = expf((float)(d+2) * c1);
  const float a0 = (float)pos * e0, a1 = (float)pos * e1;
  const float v[4] = {a.x + sinf(a0), a.y + cosf(a0), a.z + sinf(a1), a.w + cosf(a1)};
  s16x4 hv, lv;
  #pragma unroll
  for (int e=0;e<4;e++){
    const short hb = f2b(v[e]);
    hv[e] = hb;
    lv[e] = f2b(v[e] - b2f(hb));
  }
  *(s16x4*)(Hi + (size_t)row*DM + d) = hv;
  *(s16x4*)(Lo + (size_t)row*DM + d) = lv;
}

// ---------------- split-bf16 MFMA GEMM (encoder): C = A @ W^T + bias ----------
template<int ACT, int OUT_MODE>
__global__ __launch_bounds__(256, 2)
void gemm_split(const short* __restrict__ Ahi, const short* __restrict__ Alo,
                const short* __restrict__ Bhi, const short* __restrict__ Blo,
                const float* __restrict__ bias,
                float* __restrict__ C, short* __restrict__ Chi, short* __restrict__ Clo,
                int M, int N, int K)
{
  __shared__ __align__(16) short lA[2][128][40];
  __shared__ __align__(16) short lB[2][128][40];
  const int tid = threadIdx.x;
  const int m0 = blockIdx.x*128, n0 = blockIdx.y*128;
  const int lane = tid & 63, w = tid >> 6;
  const int wr = w >> 1, wc = w & 1;
  const int fr = lane & 15, fq = lane >> 4;

  f32x4 acc[4][4];
  #pragma unroll
  for (int i=0;i<4;i++)
    #pragma unroll
    for (int j=0;j<4;j++) acc[i][j] = (f32x4){0.f,0.f,0.f,0.f};

  for (int k0 = 0; k0 < K; k0 += 32) {
    __syncthreads();
    #pragma unroll
    for (int j=0;j<2;j++){
      const int cc = tid + j*256;
      const int row = cc >> 2, kq = cc & 3;
      const size_t ga = (size_t)(m0+row)*K + k0 + kq*8;
      const size_t gb = (size_t)(n0+row)*K + k0 + kq*8;
      *(s16x8*)&lA[0][row][kq*8] = *(const s16x8*)(Ahi + ga);
      *(s16x8*)&lA[1][row][kq*8] = *(const s16x8*)(Alo + ga);
      *(s16x8*)&lB[0][row][kq*8] = *(const s16x8*)(Bhi + gb);
      *(s16x8*)&lB[1][row][kq*8] = *(const s16x8*)(Blo + gb);
    }
    __syncthreads();
    s16x8 ah[4], al[4], bh[4], bl[4];
    #pragma unroll
    for (int i=0;i<4;i++){
      ah[i] = *(const s16x8*)&lA[0][wr*64+i*16+fr][fq*8];
      al[i] = *(const s16x8*)&lA[1][wr*64+i*16+fr][fq*8];
    }
    #pragma unroll
    for (int j=0;j<4;j++){
      bh[j] = *(const s16x8*)&lB[0][wc*64+j*16+fr][fq*8];
      bl[j] = *(const s16x8*)&lB[1][wc*64+j*16+fr][fq*8];
    }
    #pragma unroll
    for (int i=0;i<4;i++)
      #pragma unroll
      for (int j=0;j<4;j++){
        acc[i][j] = __builtin_amdgcn_mfma_f32_16x16x32_bf16(ah[i], bh[j], acc[i][j], 0,0,0);
        acc[i][j] = __builtin_amdgcn_mfma_f32_16x16x32_bf16(ah[i], bl[j], acc[i][j], 0,0,0);
        acc[i][j] = __builtin_amdgcn_mfma_f32_16x16x32_bf16(al[i], bh[j], acc[i][j], 0,0,0);
      }
  }
  #pragma unroll
  for (int j=0;j<4;j++){
    const int col = n0 + wc*64 + j*16 + fr;
    const float bv = bias[col];
    #pragma unroll
    for (int i=0;i<4;i++){
      const int row0 = m0 + wr*64 + i*16 + fq*4;
      #pragma unroll
      for (int r=0;r<4;r++){
        float v = acc[i][j][r] + bv;
        if (ACT==1) v = fmaxf(v, 0.f);
        const size_t idx = (size_t)(row0+r)*N + col;
        if (OUT_MODE==0 || OUT_MODE==2) C[idx] = v;
        if (OUT_MODE==1 || OUT_MODE==2){
          const short hb = f2b(v);
          Chi[idx] = hb;
          Clo[idx] = f2b(v - b2f(hb));
        }
        if (OUT_MODE==3) Chi[idx] = f2b(v);
      }
    }
  }
}

// ---------------- encoder self-attention ----
__global__ __launch_bounds__(256)
void attn_enc(const float* __restrict__ Qg, const float* __restrict__ Kg,
              const float* __restrict__ Vg, short* __restrict__ Ohi,
              short* __restrict__ Olo)
{
  const int bh = blockIdx.y;
  const int b = bh >> 4, hh = bh & 15;
  const int row = blockIdx.x*256 + threadIdx.x;
  const size_t base = ((size_t)b*TT)*DM + hh*DKH;
  float q[64];
  {
    const float* qp = Qg + base + (size_t)row*DM;
    #pragma unroll
    for (int d4=0; d4<16; d4++){
      const float4 v = *(const float4*)(qp + d4*4);
      q[d4*4+0]=v.x; q[d4*4+1]=v.y; q[d4*4+2]=v.z; q[d4*4+3]=v.w;
    }
  }
  float o[64];
  #pragma unroll
  for (int d=0;d<64;d++) o[d]=0.f;
  float m = -INFINITY, l = 0.f;
  __shared__ float Ks[64][68];
  __shared__ float Vs[64][68];
  for (int kt=0; kt<TT; kt+=64) {
    __syncthreads();
    #pragma unroll
    for (int t=0;t<4;t++){
      const int fi = threadIdx.x + t*256;
      const int j = fi>>4, dq = fi&15;
      *(float4*)&Ks[j][dq*4] = *(const float4*)(Kg + base + (size_t)(kt+j)*DM + dq*4);
      *(float4*)&Vs[j][dq*4] = *(const float4*)(Vg + base + (size_t)(kt+j)*DM + dq*4);
    }
    __syncthreads();
    for (int j=0;j<64;j++){
      float s0=0.f,s1=0.f,s2=0.f,s3=0.f;
      #pragma unroll
      for (int d=0; d<64; d+=4){
        s0 = fmaf(q[d+0], Ks[j][d+0], s0);
        s1 = fmaf(q[d+1], Ks[j][d+1], s1);
        s2 = fmaf(q[d+2], Ks[j][d+2], s2);
        s3 = fmaf(q[d+3], Ks[j][d+3], s3);
      }
      const float s = ((s0+s1)+(s2+s3)) * 0.125f;
      if (s > m) {
        const float f = __expf(m - s);
        l *= f;
        #pragma unroll
        for (int d=0;d<64;d++) o[d] *= f;
        m = s;
      }
      const float p = __expf(s - m);
      l += p;
      #pragma unroll
      for (int d=0;d<64;d++) o[d] = fmaf(p, Vs[j][d], o[d]);
    }
  }
  const float inv = 1.f / l;
  #pragma unroll
  for (int d8=0; d8<8; d8++){
    s16x8 hv, lv;
    #pragma unroll
    for (int e=0;e<8;e++){
      const float f = o[d8*8+e]*inv;
      const short hb = f2b(f);
      hv[e] = hb;
      lv[e] = f2b(f - b2f(hb));
    }
    *(s16x8*)(Ohi + base + (size_t)row*DM + d8*8) = hv;
    *(s16x8*)(Olo + base + (size_t)row*DM + d8*8) = lv;
  }
}

// encoder LayerNorm: split bf16 out
__global__ __launch_bounds__(256)
void ln_add_split(const float* __restrict__ X, const float* __restrict__ Y,
                  const float* __restrict__ g, const float* __restrict__ be,
                  short* __restrict__ Ohi, short* __restrict__ Olo)
{
  const size_t row = blockIdx.x;
  const int tid = threadIdx.x;
  const float4 a = *(const float4*)(X + row*DM + tid*4);
  const float4 b = *(const float4*)(Y + row*DM + tid*4);
  const float v0=a.x+b.x, v1=a.y+b.y, v2=a.z+b.z, v3=a.w+b.w;
  float s = v0+v1+v2+v3;
  float q = v0*v0+v1*v1+v2*v2+v3*v3;
  s = wave_sum(s); q = wave_sum(q);
  __shared__ float rs[4], rq[4];
  if ((tid&63)==0){ rs[tid>>6]=s; rq[tid>>6]=q; }
  __syncthreads();
  const float S = rs[0]+rs[1]+rs[2]+rs[3];
  const float Q = rq[0]+rq[1]+rq[2]+rq[3];
  const float mean = S * (1.f/DM);
  const float var  = Q * (1.f/DM) - mean*mean;
  const float rstd = rsqrtf(var + 1e-5f);
  const float4 gv = *(const float4*)(g  + tid*4);
  const float4 bv = *(const float4*)(be + tid*4);
  const float v[4] = {(v0-mean)*rstd*gv.x + bv.x, (v1-mean)*rstd*gv.y + bv.y,
                      (v2-mean)*rstd*gv.z + bv.z, (v3-mean)*rstd*gv.w + bv.w};
  s16x4 hv, lv;
  #pragma unroll
  for (int e=0;e<4;e++){
    const short hb = f2b(v[e]);
    hv[e] = hb;
    lv[e] = f2b(v[e] - b2f(hb));
  }
  *(s16x4*)(Ohi + row*DM + tid*4) = hv;
  *(s16x4*)(Olo + row*DM + tid*4) = lv;
}

// ================= persistent decoder =================

// sharded two-level barrier: 8 shards -> root -> broadcast flag. NB%8==0.
__device__ inline void gsync(unsigned* bars, unsigned gen){
  __syncthreads();
  if (threadIdx.x == 0){
    __threadfence();
    const int sh = blockIdx.x & 7;
    const unsigned old = __hip_atomic_fetch_add(&bars[sh*16], 1u,
        __ATOMIC_RELAXED, __HIP_MEMORY_SCOPE_AGENT);
    if (old == gen*(NB/8) - 1){
      const unsigned r = __hip_atomic_fetch_add(&bars[128], 1u,
          __ATOMIC_RELAXED, __HIP_MEMORY_SCOPE_AGENT);
      if (r == gen*8 - 1)
        __hip_atomic_store(&bars[144], gen, __ATOMIC_RELAXED, __HIP_MEMORY_SCOPE_AGENT);
    }
    while (__hip_atomic_load(&bars[144], __ATOMIC_RELAXED, __HIP_MEMORY_SCOPE_AGENT) < gen)
      __builtin_amdgcn_s_sleep(1);
    __threadfence();
  }
  __syncthreads();
}

__device__ inline f32x4 mfma3(const s16x8 ah, const s16x8 al,
                              const s16x8 bh, const s16x8 bl, f32x4 A){
  A = __builtin_amdgcn_mfma_f32_16x16x32_bf16(ah, bh, A, 0,0,0);
  A = __builtin_amdgcn_mfma_f32_16x16x32_bf16(ah, bl, A, 0,0,0);
  A = __builtin_amdgcn_mfma_f32_16x16x32_bf16(al, bh, A, 0,0,0);
  return A;
}

// 16-col-tile GEMM, wave-level K-split (4 x 256), direct global->reg fragments
// (no LDS in k-loop, no syncs -> deep compiler pipelining). LDS cross-wave reduce.
// MODE bit0: f32 out, bit1: split out. bias nullable. mr = #16-row frags (1..6).
template<int MODE, int ACT>
__device__ inline void gemm16(const short* __restrict__ Ahi, const short* __restrict__ Alo,
    const short* __restrict__ Bhi, const short* __restrict__ Blo,
    int lda, int ldb, int ldo, int c0, int kbase, int mr,
    const float* __restrict__ bias,
    float* __restrict__ outf, short* __restrict__ ohi, short* __restrict__ olo,
    char* smem)
{
  const int tid = threadIdx.x, lane = tid & 63, w = tid >> 6;
  const int fr = lane & 15, fq = lane >> 4;
  const size_t kw = (size_t)kbase + w*256 + fq*8;
  const short* Ah = Ahi + (size_t)fr*lda + kw;
  const short* Al = Alo + (size_t)fr*lda + kw;
  const short* Bh = Bhi + (size_t)(c0+fr)*ldb + kw;
  const short* Bl = Blo + (size_t)(c0+fr)*ldb + kw;
  f32x4 a0={0.f,0.f,0.f,0.f}, a1=a0, a2=a0, a3=a0, a4=a0, a5=a0;
  #pragma unroll
  for (int c=0; c<8; c++){
    const int ko = c*32;
    const s16x8 bh = *(const s16x8*)(Bh + ko);
    const s16x8 bl = *(const s16x8*)(Bl + ko);
    #define AS(i, A) if (mr > i){ \
      const s16x8 ah = *(const s16x8*)(Ah + (size_t)(i*16)*lda + ko); \
      const s16x8 al = *(const s16x8*)(Al + (size_t)(i*16)*lda + ko); \
      A = mfma3(ah, al, bh, bl, A); }
    AS(0,a0) AS(1,a1) AS(2,a2) AS(3,a3) AS(4,a4) AS(5,a5)
    #undef AS
  }
  // cross-wave reduce via LDS [4][96][17] f32
  float (*red)[96][17] = (float(*)[96][17])smem;
  #define ST(i, A) if (mr > i){ \
    red[w][i*16+fq*4+0][fr]=A[0]; red[w][i*16+fq*4+1][fr]=A[1]; \
    red[w][i*16+fq*4+2][fr]=A[2]; red[w][i*16+fq*4+3][fr]=A[3]; }
  ST(0,a0) ST(1,a1) ST(2,a2) ST(3,a3) ST(4,a4) ST(5,a5)
  #undef ST
  __syncthreads();
  const int tot = mr*256;                  // mr*16 rows x 16 cols
  for (int o=tid; o<tot; o+=256){
    const int row = o >> 4, col = o & 15;
    float s = red[0][row][col] + red[1][row][col] + red[2][row][col] + red[3][row][col];
    if (bias) s += bias[c0 + col];
    if (ACT) s = fmaxf(s, 0.f);
    const size_t idx = (size_t)row*ldo + c0 + col;
    if (MODE & 1) outf[idx] = s;
    if (MODE & 2){
      const short hb = f2b(s);
      ohi[idx] = hb;
      olo[idx] = f2b(s - b2f(hb));
    }
  }
}

__device__ inline void prep_unit(short* __restrict__ Dhi, short* __restrict__ Dlo,
                                 const float* __restrict__ tok, int r)
{
  const int i = r >> 2;
  const int d = threadIdx.x*4;
  const float4 a = *(const float4*)(tok + (size_t)r*DM + d);
  const float c1 = -9.210340371976184f / 1024.0f;
  const float e0 = expf((float)d * c1);
  const float e1 = expf((float)(d+2) * c1);
  const float a0 = (float)i * e0, a1 = (float)i * e1;
  const float v[4] = {a.x + sinf(a0), a.y + cosf(a0), a.z + sinf(a1), a.w + cosf(a1)};
  s16x4 hv, lv;
  #pragma unroll
  for (int e=0;e<4;e++){
    const short hb = f2b(v[e]);
    hv[e] = hb;
    lv[e] = f2b(v[e] - b2f(hb));
  }
  *(s16x4*)(Dhi + (size_t)r*DM + d) = hv;
  *(s16x4*)(Dlo + (size_t)r*DM + d) = lv;
}

// self-attention (f32 Q/K/V with bias pre-added by gemm16), packed rows, split out
__device__ inline void attn_self_unit(const float* __restrict__ Qg,
    const float* __restrict__ Kg, const float* __restrict__ Vg,
    short* __restrict__ Ohi, short* __restrict__ Olo, int n, int bh, char* smem)
{
  const int b = bh >> 4, hh = bh & 15;
  const size_t base = (size_t)b*DM + hh*DKH;
  float (*Qs)[68] = (float(*)[68])smem;
  float (*Ks)[68] = (float(*)[68])(smem + 6528);
  float (*Vs)[68] = (float(*)[68])(smem + 13056);
  float (*P)[28]  = (float(*)[28])(smem + 19584);
  const int tid = threadIdx.x;
  for (int t = tid; t < 3*n*16; t += 256){
    const int tensor = t / (n*16);
    const int fi = t - tensor*(n*16);
    const int row = fi >> 4, q4 = fi & 15;
    const float* src = (tensor==0?Qg:(tensor==1?Kg:Vg)) + base + (size_t)(row*4)*DM + q4*4;
    float (*dst)[68] = (tensor==0?Qs:(tensor==1?Ks:Vs));
    *(float4*)&dst[row][q4*4] = *(const float4*)src;
  }
  __syncthreads();
  for (int idx = tid; idx < n*n; idx += 256){
    const int i = idx / n, j = idx - i*n;
    float s0=0.f,s1=0.f,s2=0.f,s3=0.f;
    #pragma unroll
    for (int d=0; d<64; d+=4){
      s0 = fmaf(Qs[i][d+0], Ks[j][d+0], s0);
      s1 = fmaf(Qs[i][d+1], Ks[j][d+1], s1);
      s2 = fmaf(Qs[i][d+2], Ks[j][d+2], s2);
      s3 = fmaf(Qs[i][d+3], Ks[j][d+3], s3);
    }
    P[i][j] = ((s0+s1)+(s2+s3))*0.125f;
  }
  __syncthreads();
  if (tid < n){
    float mm = -INFINITY;
    for (int j=0;j<n;j++) mm = fmaxf(mm, P[tid][j]);
    float l = 0.f;
    for (int j=0;j<n;j++){ const float p = __expf(P[tid][j]-mm); P[tid][j]=p; l+=p; }
    const float inv = 1.f/l;
    for (int j=0;j<n;j++) P[tid][j] *= inv;
  }
  __syncthreads();
  for (int idx = tid; idx < n*64; idx += 256){
    const int i = idx >> 6, d = idx & 63;
    float s = 0.f;
    for (int j=0;j<n;j++) s = fmaf(P[i][j], Vs[j][d], s);
    const short hb = f2b(s);
    const size_t o = base + (size_t)(i*4)*DM + d;
    Ohi[o] = hb;
    Olo[o] = f2b(s - b2f(hb));
  }
}

__device__ inline void cross_part_unit(const float* __restrict__ Qg,
    const short* __restrict__ Kc, const short* __restrict__ Vc,
    float* __restrict__ opart, float* __restrict__ mlpart, int n, int unit, char* smem)
{
  const int ks = unit & (CSPLIT-1), bh = unit >> 3;
  const int b = bh >> 4, hh = bh & 15;
  float (*Qs)[68]  = (float(*)[68])smem;
  short (*KVs)[72] = (short(*)[72])(smem + 6528);
  float (*S)[132]  = (float(*)[132])(smem + 24960);
  const int tid = threadIdx.x;
  // REQUIRED: blocks run multiple units back-to-back; protect smem (KVs/S) still
  // being read by trailing waves of the previous unit (r7 bug: this was dropped).
  __syncthreads();
  const size_t qbase = (size_t)b*DM + hh*DKH;
  for (int t=tid; t<n*16; t+=256){
    const int row = t>>4, q4 = t&15;
    *(float4*)&Qs[row][q4*4] = *(const float4*)(Qg + qbase + (size_t)(row*4)*DM + q4*4);
  }
  const size_t kbase = ((size_t)b*TT + (size_t)ks*CKEYS)*DM + hh*DKH;
  for (int t=tid; t<CKEYS*8; t+=256){
    const int row = t>>3, d8 = t&7;
    *(s16x8*)&KVs[row][d8*8] = *(const s16x8*)(Kc + kbase + (size_t)row*DM + d8*8);
  }
  __syncthreads();
  for (int idx=tid; idx<n*128; idx+=256){
    const int i = idx >> 7, j = idx & 127;
    float s0=0.f,s1=0.f,s2=0.f,s3=0.f;
    #pragma unroll
    for (int d=0; d<64; d+=4){
      s0 = fmaf(Qs[i][d+0], b2f(KVs[j][d+0]), s0);
      s1 = fmaf(Qs[i][d+1], b2f(KVs[j][d+1]), s1);
      s2 = fmaf(Qs[i][d+2], b2f(KVs[j][d+2]), s2);
      s3 = fmaf(Qs[i][d+3], b2f(KVs[j][d+3]), s3);
    }
    S[i][j] = ((s0+s1)+(s2+s3))*0.125f;
  }
  __syncthreads();
  for (int t=tid; t<CKEYS*8; t+=256){
    const int row = t>>3, d8 = t&7;
    *(s16x8*)&KVs[row][d8*8] = *(const s16x8*)(Vc + kbase + (size_t)row*DM + d8*8);
  }
  if (tid < n){
    float mm=-INFINITY;
    for (int j=0;j<CKEYS;j++) mm = fmaxf(mm, S[tid][j]);
    float l=0.f;
    for (int j=0;j<CKEYS;j++){ const float p=__expf(S[tid][j]-mm); S[tid][j]=p; l+=p; }
    mlpart[((size_t)bh*CSPLIT+ks)*(2*NSTEP) + tid*2+0] = mm;
    mlpart[((size_t)bh*CSPLIT+ks)*(2*NSTEP) + tid*2+1] = l;
  }
  __syncthreads();
  for (int idx=tid; idx<n*64; idx+=256){
    const int i = idx >> 6, d = idx & 63;
    float s=0.f;
    for (int j=0;j<CKEYS;j++) s = fmaf(S[i][j], b2f(KVs[j][d]), s);
    opart[(((size_t)bh*CSPLIT+ks)*NSTEP + i)*DKH + d] = s;
  }
}

__device__ inline void comb_unit(const float* __restrict__ opart,
    const float* __restrict__ mlp, short* __restrict__ Ohi, short* __restrict__ Olo,
    int n, int bh)
{
  const int b = bh >> 4, hh = bh & 15;
  for (int idx=threadIdx.x; idx<n*64; idx+=256){
    const int i = idx >> 6, d = idx & 63;
    float M = -INFINITY;
    #pragma unroll
    for (int s=0;s<CSPLIT;s++)
      M = fmaxf(M, mlp[((size_t)bh*CSPLIT+s)*(2*NSTEP) + i*2]);
    float acc = 0.f, L = 0.f;
    #pragma unroll
    for (int s=0;s<CSPLIT;s++){
      const float mm = mlp[((size_t)bh*CSPLIT+s)*(2*NSTEP) + i*2+0];
      const float ll = mlp[((size_t)bh*CSPLIT+s)*(2*NSTEP) + i*2+1];
      const float f = __expf(mm - M);
      acc = fmaf(f, opart[(((size_t)bh*CSPLIT+s)*NSTEP + i)*DKH + d], acc);
      L   = fmaf(f, ll, L);
    }
    const float v = acc / L;
    const short hb = f2b(v);
    const size_t o = ((size_t)(i*4+b))*DM + hh*DKH + d;
    Ohi[o] = hb;
    Olo[o] = f2b(v - b2f(hb));
  }
}

// reduce FFN2 partials(4) + bias + residual -> LN -> dbuf f32 + split
__device__ inline void ln_unit(const float* __restrict__ part, const float* __restrict__ bias,
    const float* __restrict__ X, const float* __restrict__ g, const float* __restrict__ be,
    float* __restrict__ Outf, short* __restrict__ Ohi, short* __restrict__ Olo,
    int row, char* smem)
{
  float* rs = (float*)smem;
  float* rq = rs + 4;
  const int tid = threadIdx.x;
  float a0=0.f,a1=0.f,a2=0.f,a3=0.f;
  #pragma unroll
  for (int ks=0; ks<4; ks++){
    const float4 p = *(const float4*)(part + (size_t)ks*PSTRIDE + (size_t)row*DM + tid*4);
    a0+=p.x; a1+=p.y; a2+=p.z; a3+=p.w;
  }
  const float4 bvv = *(const float4*)(bias + tid*4);
  const float4 xv  = *(const float4*)(X + (size_t)row*DM + tid*4);
  const float v0=a0+bvv.x+xv.x, v1=a1+bvv.y+xv.y, v2=a2+bvv.z+xv.z, v3=a3+bvv.w+xv.w;
  float s = v0+v1+v2+v3;
  float q = v0*v0+v1*v1+v2*v2+v3*v3;
  s = wave_sum(s); q = wave_sum(q);
  if ((tid&63)==0){ rs[tid>>6]=s; rq[tid>>6]=q; }
  __syncthreads();
  const float S = rs[0]+rs[1]+rs[2]+rs[3];
  const float Q = rq[0]+rq[1]+rq[2]+rq[3];
  const float mean = S * (1.f/DM);
  const float var  = Q * (1.f/DM) - mean*mean;
  const float rstd = rsqrtf(var + 1e-5f);
  const float4 gv = *(const float4*)(g  + tid*4);
  const float4 bv2 = *(const float4*)(be + tid*4);
  const float v[4] = {(v0-mean)*rstd*gv.x + bv2.x, (v1-mean)*rstd*gv.y + bv2.y,
                      (v2-mean)*rstd*gv.z + bv2.z, (v3-mean)*rstd*gv.w + bv2.w};
  float4 of; of.x=v[0]; of.y=v[1]; of.z=v[2]; of.w=v[3];
  *(float4*)(Outf + (size_t)row*DM + tid*4) = of;
  s16x4 hv, lv;
  #pragma unroll
  for (int e=0;e<4;e++){
    const short hb = f2b(v[e]);
    hv[e] = hb;
    lv[e] = f2b(v[e] - b2f(hb));
  }
  *(s16x4*)(Ohi + (size_t)row*DM + tid*4) = hv;
  *(s16x4*)(Olo + (size_t)row*DM + tid*4) = lv;
}

__device__ inline void out_unit(const float* __restrict__ Dv, const float* __restrict__ outW,
    const float* __restrict__ outB, const float* __restrict__ tembW,
    const float* __restrict__ tembB, float* __restrict__ dout, float* __restrict__ tok,
    int s, int b, char* smem)
{
  float* red = (float*)smem;
  float* stepv = red + 4;
  const int tid = threadIdx.x;
  const float* drow = Dv + ((size_t)(s*4 + b))*DM;
  const float4 dv4 = *(const float4*)(drow + tid*4);
  const float4 wv = *(const float4*)(outW + tid*4);
  float p = dv4.x*wv.x + dv4.y*wv.y + dv4.z*wv.z + dv4.w*wv.w;
  p = wave_sum(p);
  if ((tid&63)==0) red[tid>>6] = p;
  __syncthreads();
  if (tid==0){
    const float sv = red[0]+red[1]+red[2]+red[3] + outB[0];
    stepv[0] = sv;
    dout[b*NSTEP + s] = sv;
  }
  __syncthreads();
  const float sv = stepv[0];
  if (s+1 < NSTEP){
    const int d = tid*4;
    const float4 tw = *(const float4*)(tembW + d);
    const float4 tb = *(const float4*)(tembB + d);
    float4 e;
    e.x = fmaf(sv, tw.x, tb.x); e.y = fmaf(sv, tw.y, tb.y);
    e.z = fmaf(sv, tw.z, tb.z); e.w = fmaf(sv, tw.w, tb.w);
    *(float4*)(tok + ((size_t)((s+1)*4 + b))*DM + d) = e;
  }
}

__global__ __launch_bounds__(256, 2)
void dec_persist(const short* __restrict__ dwq, const short* __restrict__ dwk,
                 const short* __restrict__ dwv, const short* __restrict__ dwo,
                 const short* __restrict__ fw1h, const short* __restrict__ fw1l,
                 const short* __restrict__ fw2h, const short* __restrict__ fw2l,
                 const float* __restrict__ bq, const float* __restrict__ bk,
                 const float* __restrict__ bv, const float* __restrict__ bo,
                 const float* __restrict__ fb1, const float* __restrict__ fb2,
                 const short* __restrict__ kcb, const short* __restrict__ vcb,
                 const float* __restrict__ nd_g, const float* __restrict__ nd_b,
                 const float* __restrict__ outW, const float* __restrict__ outB,
                 const float* __restrict__ tembW, const float* __restrict__ tembB,
                 float* __restrict__ dout, float* __restrict__ tok,
                 float* __restrict__ dbuf, float* __restrict__ dq,
                 float* __restrict__ dk, float* __restrict__ dv,
                 short* __restrict__ dbhi, short* __restrict__ dblo,
                 short* __restrict__ dahi, short* __restrict__ dalo,
                 short* __restrict__ dmhi, short* __restrict__ dmlo,
                 float* __restrict__ part, float* __restrict__ opart,
                 float* __restrict__ mlp, unsigned* __restrict__ bars)
{
  __shared__ __align__(16) char smem[37632];
  const int bid = blockIdx.x;
  unsigned gen = 0;
  const size_t MM = (size_t)DM*DM;
  for (int s=0; s<NSTEP; ++s){
    const int n = s+1, rows = 4*n;
    const int mr = (rows + 15) >> 4;
    if (bid < NROW) prep_unit(dbhi, dblo, tok, bid);
    gsync(bars, ++gen);
    for (int l=0; l<NL; ++l){
      const short* qh = dwq + (size_t)l*2*MM; const short* ql = qh + MM;
      const short* kh = dwk + (size_t)l*2*MM; const short* kl = kh + MM;
      const short* vh = dwv + (size_t)l*2*MM; const short* vl = vh + MM;
      const short* oh = dwo + (size_t)l*2*MM; const short* ol = oh + MM;
      const float* lbq = bq + (size_t)l*DM;
      const float* lbk = bk + (size_t)l*DM;
      const float* lbv = bv + (size_t)l*DM;
      const float* lbo = bo + (size_t)l*DM;
      // --- QKV: 192 units (3 mats x 64 col-tiles), f32 out + bias ---
      if (bid < 192){
        const int mat = bid >> 6, t = bid & 63;
        gemm16<1,0>(dbhi, dblo,
                    mat==0?qh:(mat==1?kh:vh), mat==0?ql:(mat==1?kl:vl),
                    DM, DM, DM, t*16, 0, mr,
                    mat==0?lbq:(mat==1?lbk:lbv),
                    mat==0?dq:(mat==1?dk:dv), nullptr, nullptr, smem);
      }
      gsync(bars, ++gen);
      // --- self-attn: 64 units ---
      if (bid < 64) attn_self_unit(dq, dk, dv, dahi, dalo, n, bid, smem);
      gsync(bars, ++gen);
      // --- self-O: 64 units, split out ---
      if (bid < 64)
        gemm16<2,0>(dahi, dalo, oh, ol, DM, DM, DM, bid*16, 0, mr, lbo,
                    nullptr, dbhi, dblo, smem);
      gsync(bars, ++gen);
      // --- cross-Q: 64 units, f32 out ---
      if (bid < 64)
        gemm16<1,0>(dbhi, dblo, qh, ql, DM, DM, DM, bid*16, 0, mr, lbq,
                    dq, nullptr, nullptr, smem);
      gsync(bars, ++gen);
      // --- cross-attn partials: 512 units ---
      for (int u=bid; u<64*CSPLIT; u+=NB)
        cross_part_unit(dq, kcb + (size_t)l*BT*DM, vcb + (size_t)l*BT*DM,
                        opart, mlp, n, u, smem);
      gsync(bars, ++gen);
      if (bid < 64) comb_unit(opart, mlp, dahi, dalo, n, bid);
      gsync(bars, ++gen);
      // --- cross-O: 64 units, f32 + split ---
      if (bid < 64)
        gemm16<3,0>(dahi, dalo, oh, ol, DM, DM, DM, bid*16, 0, mr, lbo,
                    dbuf, dbhi, dblo, smem);
      gsync(bars, ++gen);
      // --- FFN1: 256 units (4096/16 col-tiles), relu + split out ---
      if (bid < 256)
        gemm16<2,1>(dbhi, dblo, fw1h, fw1l, DM, DM, DFFN, bid*16, 0, mr, fb1,
                    nullptr, dmhi, dmlo, smem);
      gsync(bars, ++gen);
      // --- FFN2: 256 units (64 col-tiles x KS4), f32 partials, no bias ---
      if (bid < 256){
        const int t = bid >> 2, ks = bid & 3;
        gemm16<1,0>(dmhi, dmlo, fw2h, fw2l, DFFN, DFFN, DM, t*16, ks*1024, mr,
                    nullptr, part + (size_t)ks*PSTRIDE, nullptr, nullptr, smem);
      }
      gsync(bars, ++gen);
      // --- LN (reduce 4 partials + bias + residual): rows units ---
      if (bid < rows)
        ln_unit(part, fb2, dbuf, nd_g, nd_b, dbuf, dbhi, dblo, bid, smem);
      gsync(bars, ++gen);
    }
    if (bid < BB) out_unit(dbuf, outW, outB, tembW, tembB, dout, tok, s, bid, smem);
    gsync(bars, ++gen);
  }
}

// ---------------- orchestration ----------------
extern "C" void kernel_launch(void* const* d_in, const int* in_sizes, int n_in,
                              void* d_out, int out_size, void* d_ws, size_t ws_size,
                              hipStream_t stream)
{
  (void)in_sizes; (void)n_in; (void)out_size; (void)ws_size;
  const float* x      = (const float*)d_in[0];
  const float* in_W   = (const float*)d_in[1];
  const float* in_b   = (const float*)d_in[2];
  const float* enc_Wq = (const float*)d_in[3];
  const float* enc_bq = (const float*)d_in[4];
  const float* enc_Wk = (const float*)d_in[5];
  const float* enc_bk = (const float*)d_in[6];
  const float* enc_Wv = (const float*)d_in[7];
  const float* enc_bv = (const float*)d_in[8];
  const float* enc_Wo = (const float*)d_in[9];
  const float* enc_bo = (const float*)d_in[10];
  const float* dec_Wq = (const float*)d_in[11];
  const float* dec_bq = (const float*)d_in[12];
  const float* dec_Wk = (const float*)d_in[13];
  const float* dec_bk = (const float*)d_in[14];
  const float* dec_Wv = (const float*)d_in[15];
  const float* dec_bv = (const float*)d_in[16];
  const float* dec_Wo = (const float*)d_in[17];
  const float* dec_bo = (const float*)d_in[18];
  const float* ffe_W1 = (const float*)d_in[19];
  const float* ffe_b1 = (const float*)d_in[20];
  const float* ffe_W2 = (const float*)d_in[21];
  const float* ffe_b2 = (const float*)d_in[22];
  const float* ffd_W1 = (const float*)d_in[23];
  const float* ffd_b1 = (const float*)d_in[24];
  const float* ffd_W2 = (const float*)d_in[25];
  const float* ffd_b2 = (const float*)d_in[26];
  const float* ne_g   = (const float*)d_in[27];
  const float* ne_b   = (const float*)d_in[28];
  const float* nd_g   = (const float*)d_in[29];
  const float* nd_b   = (const float*)d_in[30];
  const float* out_W  = (const float*)d_in[31];
  const float* out_b  = (const float*)d_in[32];
  const float* temb_W = (const float*)d_in[33];
  const float* temb_b = (const float*)d_in[34];
  float* dout = (float*)d_out;

  float* ws = (float*)d_ws;
  size_t off = 0;
  auto alloc  = [&](size_t n){ n = (n+3)&~(size_t)3; float* p = ws + off; off += n; return p; };
  auto allocS = [&](size_t n){ size_t nf = ((n+1)/2 + 3)&~(size_t)3; short* p = (short*)(ws + off); off += nf; return p; };

  // activations (encoder)
  short* hshi = allocS((size_t)BT*DM);
  short* hslo = allocS((size_t)BT*DM);
  float* h    = alloc((size_t)BT*DM);
  float* hn   = h;
  float* t0   = alloc((size_t)BT*DM);
  float* t1   = alloc((size_t)BT*DM);
  float* t2   = alloc((size_t)BT*DM);
  short* t3hi = allocS((size_t)BT*DM);
  short* t3lo = allocS((size_t)BT*DM);
  short* hnhi = allocS((size_t)BT*DM);
  short* hnlo = allocS((size_t)BT*DM);
  float* t4   = alloc((size_t)BT*DM);          // FFN2 out (encoder) UNION part (decoder)
  float* part = t4;
  short* fmhi = (short*)t0;
  short* fmlo = fmhi + (size_t)BT*DFFN;
  // bf16 K/V cross-attn cache
  short* kcb  = allocS((size_t)NL*BT*DM);
  short* vcb  = allocS((size_t)NL*BT*DM);
  // split inputs
  short* xshi = allocS((size_t)BT*64);
  short* xslo = allocS((size_t)BT*64);
  short* iwhi = allocS((size_t)DM*64);
  short* iwlo = allocS((size_t)DM*64);
  // per-layer reused weight slots (encoder + KV build)
  short* w0hi = allocS((size_t)DM*DM); short* w0lo = allocS((size_t)DM*DM);
  short* w1hi = allocS((size_t)DM*DM); short* w1lo = allocS((size_t)DM*DM);
  short* w2hi = allocS((size_t)DM*DM); short* w2lo = allocS((size_t)DM*DM);
  short* w3hi = allocS((size_t)DM*DM); short* w3lo = allocS((size_t)DM*DM);
  short* wfhi = allocS((size_t)DFFN*DM); short* wflo = allocS((size_t)DFFN*DM);   // ffe_W1
  short* wf2hi= allocS((size_t)DM*DFFN); short* wf2lo= allocS((size_t)DM*DFFN);   // ffe_W2
  // decoder buffers (packed rows r = i*4+b)
  float* tok  = alloc((size_t)MD*DM);
  float* dbuf = alloc((size_t)MD*DM);
  float* dq   = alloc((size_t)MD*DM);
  float* dk   = alloc((size_t)MD*DM);
  float* dv_  = alloc((size_t)MD*DM);
  short* dbhi = allocS((size_t)MD*DM);  short* dblo = allocS((size_t)MD*DM);
  short* dahi = allocS((size_t)MD*DM);  short* dalo = allocS((size_t)MD*DM);
  short* dmhi = allocS((size_t)MD*DFFN);short* dmlo = allocS((size_t)MD*DFFN);
  float* opart= alloc((size_t)BB*NH*CSPLIT*NSTEP*DKH);
  float* mlp  = alloc((size_t)BB*NH*CSPLIT*2*NSTEP);
  unsigned* bars = (unsigned*)alloc(256);

  // decoder split weights aliased onto dead-after-encoder buffers
  const size_t MM = (size_t)DM*DM;
  short* dwq = (short*)t0;
  short* dwk = (short*)t1;
  short* dwv = (short*)t2;
  short* dwo = (short*)h;
  short* fw1h = t3hi; short* fw1l = t3lo;
  short* fw2h = hnhi; short* fw2l = hnlo;

  auto cvt = [&](const float* src, short* hi, short* lo, size_t n){
    split_kernel<<<(int)((n/8 + 255)/256), 256, 0, stream>>>(src, hi, lo, (int)(n/8));
  };

  cvt(x,    xshi, xslo, (size_t)BT*64);
  cvt(in_W, iwhi, iwlo, (size_t)DM*64);
  cvt(ffe_W1, wfhi,  wflo,  (size_t)DFFN*DM);   // layer-invariant: hoisted
  cvt(ffe_W2, wf2hi, wf2lo, (size_t)DM*DFFN);
  zero_kernel<<<(MD*DM+255)/256, 256, 0, stream>>>(tok, MD*DM);
  zero_kernel<<<1, 256, 0, stream>>>((float*)bars, 256);

  // input projection + PE -> split
  gemm_split<0,0><<<dim3(BT/128, DM/128), 256, 0, stream>>>(
      xshi, xslo, iwhi, iwlo, in_b, h, (short*)nullptr, (short*)nullptr, BT, DM, 64);
  add_pe_split<<<BT, 256, 0, stream>>>(h, hshi, hslo);

  // ---- encoder ----
  for (int l=0; l<NL; ++l) {
    const size_t wo = (size_t)l*DM*DM, bo_ = (size_t)l*DM;
    cvt(enc_Wq+wo, w0hi, w0lo, MM);
    cvt(enc_Wk+wo, w1hi, w1lo, MM);
    cvt(enc_Wv+wo, w2hi, w2lo, MM);
    cvt(enc_Wo+wo, w3hi, w3lo, MM);
    gemm_split<0,0><<<dim3(32,8),256,0,stream>>>(hshi, hslo, w0hi, w0lo, enc_bq+bo_,
        t0, (short*)nullptr, (short*)nullptr, BT, DM, DM);
    gemm_split<0,0><<<dim3(32,8),256,0,stream>>>(hshi, hslo, w1hi, w1lo, enc_bk+bo_,
        t1, (short*)nullptr, (short*)nullptr, BT, DM, DM);
    gemm_split<0,0><<<dim3(32,8),256,0,stream>>>(hshi, hslo, w2hi, w2lo, enc_bv+bo_,
        t2, (short*)nullptr, (short*)nullptr, BT, DM, DM);
    attn_enc<<<dim3(TT/256, BB*NH),256,0,stream>>>(t0, t1, t2, t3hi, t3lo);
    gemm_split<0,2><<<dim3(32,8),256,0,stream>>>(t3hi, t3lo, w3hi, w3lo, enc_bo+bo_,
        hn, hnhi, hnlo, BT, DM, DM);
    gemm_split<1,1><<<dim3(32,32),256,0,stream>>>(hnhi, hnlo, wfhi, wflo, ffe_b1,
        (float*)nullptr, fmhi, fmlo, BT, DFFN, DM);
    gemm_split<0,0><<<dim3(32,8),256,0,stream>>>(fmhi, fmlo, wf2hi, wf2lo, ffe_b2,
        t4, (short*)nullptr, (short*)nullptr, BT, DM, DFFN);
    ln_add_split<<<BT,256,0,stream>>>(hn, t4, ne_g, ne_b, hshi, hslo);
  }

  // ---- cross-attention K/V cache (bf16) ----
  for (int l=0; l<NL; ++l) {
    const size_t wo = (size_t)l*DM*DM, bo_ = (size_t)l*DM;
    cvt(dec_Wk+wo, w0hi, w0lo, MM);
    cvt(dec_Wv+wo, w1hi, w1lo, MM);
    gemm_split<0,3><<<dim3(32,8),256,0,stream>>>(hshi, hslo, w0hi, w0lo, dec_bk+bo_,
        (float*)nullptr, kcb+(size_t)l*BT*DM, (short*)nullptr, BT, DM, DM);
    gemm_split<0,3><<<dim3(32,8),256,0,stream>>>(hshi, hslo, w1hi, w1lo, dec_bv+bo_,
        (float*)nullptr, vcb+(size_t)l*BT*DM, (short*)nullptr, BT, DM, DM);
  }

  // ---- decoder split weights (once; into dead encoder buffers) ----
  for (int l=0; l<NL; ++l) {
    const size_t wo = (size_t)l*DM*DM;
    cvt(dec_Wq+wo, dwq + (size_t)l*2*MM, dwq + (size_t)l*2*MM + MM, MM);
    cvt(dec_Wk+wo, dwk + (size_t)l*2*MM, dwk + (size_t)l*2*MM + MM, MM);
    cvt(dec_Wv+wo, dwv + (size_t)l*2*MM, dwv + (size_t)l*2*MM + MM, MM);
    cvt(dec_Wo+wo, dwo + (size_t)l*2*MM, dwo + (size_t)l*2*MM + MM, MM);
  }
  cvt(ffd_W1, fw1h, fw1l, (size_t)DFFN*DM);
  cvt(ffd_W2, fw2h, fw2l, (size_t)DM*DFFN);

  // ---- persistent decoder: one launch, all 24 steps, 384 blocks ----
  dec_persist<<<NB, 256, 0, stream>>>(
      dwq, dwk, dwv, dwo, fw1h, fw1l, fw2h, fw2l,
      dec_bq, dec_bk, dec_bv, dec_bo, ffd_b1, ffd_b2,
      kcb, vcb, nd_g, nd_b, out_W, out_b, temb_W, temb_b,
      dout, tok, dbuf, dq, dk, dv_,
      dbhi, dblo, dahi, dalo, dmhi, dmlo,
      part, opart, mlp, bars);
}

// Round 9
// 18882.384 us; speedup vs baseline: 2.0033x; 2.0033x over previous
//
#include <hip/hip_runtime.h>
#include <math.h>

#define DM    1024
#define NH    16
#define DKH   64
#define NL    4
#define DFFN  4096
#define BB    4
#define TT    1024
#define NSTEP 24
#define BT    (BB*TT)      // 4096 encoder rows
#define MD    (BB*NSTEP)   // 96 decoder rows max (packed: row = i*4 + b)
#define CSPLIT 8
#define CKEYS  (TT/CSPLIT) // 128 keys per cross-attn split
#define NROW  96
#define PSTRIDE ((size_t)NROW*DM)      // FFN2 partial stride (f32)

typedef __attribute__((ext_vector_type(8))) short s16x8;
typedef __attribute__((ext_vector_type(4))) short s16x4;
typedef __attribute__((ext_vector_type(4))) float f32x4;

__device__ inline short f2b(float f){
  unsigned u = __float_as_uint(f);
  u += 0x7fffu + ((u>>16)&1u);          // round-to-nearest-even
  return (short)(u>>16);
}
__device__ inline float b2f(short h){
  return __uint_as_float(((unsigned)(unsigned short)h)<<16);
}

__device__ inline float wave_sum(float v){
  #pragma unroll
  for (int off=1; off<64; off<<=1) v += __shfl_xor(v, off, 64);
  return v;
}

// ---------------- f32 -> (hi,lo) bf16 split ----------------
__global__ __launch_bounds__(256)
void split_kernel(const float* __restrict__ X, short* __restrict__ Hi,
                  short* __restrict__ Lo, int n8)
{
  const size_t i = (size_t)blockIdx.x*256 + threadIdx.x;
  if (i >= (size_t)n8) return;
  const float4 v0 = *(const float4*)(X + i*8);
  const float4 v1 = *(const float4*)(X + i*8 + 4);
  const float f[8] = {v0.x,v0.y,v0.z,v0.w,v1.x,v1.y,v1.z,v1.w};
  s16x8 hv, lv;
  #pragma unroll
  for (int e=0;e<8;e++){
    const short h = f2b(f[e]);
    hv[e] = h;
    lv[e] = f2b(f[e] - b2f(h));
  }
  *(s16x8*)(Hi + i*8) = hv;
  *(s16x8*)(Lo + i*8) = lv;
}

__global__ void zero_kernel(float* __restrict__ p, int n) {
  int i = blockIdx.x*256 + threadIdx.x;
  if (i < n) p[i] = 0.f;
}

// h[row] + pe[row%TT] -> split bf16 (encoder)
__global__ __launch_bounds__(256)
void add_pe_split(const float* __restrict__ h, short* __restrict__ Hi,
                  short* __restrict__ Lo)
{
  const int row = blockIdx.x;
  const int pos = row & (TT-1);
  const int d = threadIdx.x*4;
  const float4 a = *(const float4*)(h + (size_t)row*DM + d);
  const float c1 = -9.210340371976184f / 1024.0f;
  const float e0 = expf((float)d * c1);
  const float e1 = expf((float)(d+2) * c1);
  const float a0 = (float)pos * e0, a1 = (float)pos * e1;
  const float v[4] = {a.x + sinf(a0), a.y + cosf(a0), a.z + sinf(a1), a.w + cosf(a1)};
  s16x4 hv, lv;
  #pragma unroll
  for (int e=0;e<4;e++){
    const short hb = f2b(v[e]);
    hv[e] = hb;
    lv[e] = f2b(v[e] - b2f(hb));
  }
  *(s16x4*)(Hi + (size_t)row*DM + d) = hv;
  *(s16x4*)(Lo + (size_t)row*DM + d) = lv;
}

// ---------------- split-bf16 MFMA GEMM (encoder): C = A @ W^T + bias ----------
template<int ACT, int OUT_MODE>
__global__ __launch_bounds__(256, 2)
void gemm_split(const short* __restrict__ Ahi, const short* __restrict__ Alo,
                const short* __restrict__ Bhi, const short* __restrict__ Blo,
                const float* __restrict__ bias,
                float* __restrict__ C, short* __restrict__ Chi, short* __restrict__ Clo,
                int M, int N, int K)
{
  __shared__ __align__(16) short lA[2][128][40];
  __shared__ __align__(16) short lB[2][128][40];
  const int tid = threadIdx.x;
  const int m0 = blockIdx.x*128, n0 = blockIdx.y*128;
  const int lane = tid & 63, w = tid >> 6;
  const int wr = w >> 1, wc = w & 1;
  const int fr = lane & 15, fq = lane >> 4;

  f32x4 acc[4][4];
  #pragma unroll
  for (int i=0;i<4;i++)
    #pragma unroll
    for (int j=0;j<4;j++) acc[i][j] = (f32x4){0.f,0.f,0.f,0.f};

  for (int k0 = 0; k0 < K; k0 += 32) {
    __syncthreads();
    #pragma unroll
    for (int j=0;j<2;j++){
      const int cc = tid + j*256;
      const int row = cc >> 2, kq = cc & 3;
      const size_t ga = (size_t)(m0+row)*K + k0 + kq*8;
      const size_t gb = (size_t)(n0+row)*K + k0 + kq*8;
      *(s16x8*)&lA[0][row][kq*8] = *(const s16x8*)(Ahi + ga);
      *(s16x8*)&lA[1][row][kq*8] = *(const s16x8*)(Alo + ga);
      *(s16x8*)&lB[0][row][kq*8] = *(const s16x8*)(Bhi + gb);
      *(s16x8*)&lB[1][row][kq*8] = *(const s16x8*)(Blo + gb);
    }
    __syncthreads();
    s16x8 ah[4], al[4], bh[4], bl[4];
    #pragma unroll
    for (int i=0;i<4;i++){
      ah[i] = *(const s16x8*)&lA[0][wr*64+i*16+fr][fq*8];
      al[i] = *(const s16x8*)&lA[1][wr*64+i*16+fr][fq*8];
    }
    #pragma unroll
    for (int j=0;j<4;j++){
      bh[j] = *(const s16x8*)&lB[0][wc*64+j*16+fr][fq*8];
      bl[j] = *(const s16x8*)&lB[1][wc*64+j*16+fr][fq*8];
    }
    #pragma unroll
    for (int i=0;i<4;i++)
      #pragma unroll
      for (int j=0;j<4;j++){
        acc[i][j] = __builtin_amdgcn_mfma_f32_16x16x32_bf16(ah[i], bh[j], acc[i][j], 0,0,0);
        acc[i][j] = __builtin_amdgcn_mfma_f32_16x16x32_bf16(ah[i], bl[j], acc[i][j], 0,0,0);
        acc[i][j] = __builtin_amdgcn_mfma_f32_16x16x32_bf16(al[i], bh[j], acc[i][j], 0,0,0);
      }
  }
  #pragma unroll
  for (int j=0;j<4;j++){
    const int col = n0 + wc*64 + j*16 + fr;
    const float bv = bias[col];
    #pragma unroll
    for (int i=0;i<4;i++){
      const int row0 = m0 + wr*64 + i*16 + fq*4;
      #pragma unroll
      for (int r=0;r<4;r++){
        float v = acc[i][j][r] + bv;
        if (ACT==1) v = fmaxf(v, 0.f);
        const size_t idx = (size_t)(row0+r)*N + col;
        if (OUT_MODE==0 || OUT_MODE==2) C[idx] = v;
        if (OUT_MODE==1 || OUT_MODE==2){
          const short hb = f2b(v);
          Chi[idx] = hb;
          Clo[idx] = f2b(v - b2f(hb));
        }
        if (OUT_MODE==3) Chi[idx] = f2b(v);
      }
    }
  }
}

// ---------------- encoder self-attention ----
__global__ __launch_bounds__(256)
void attn_enc(const float* __restrict__ Qg, const float* __restrict__ Kg,
              const float* __restrict__ Vg, short* __restrict__ Ohi,
              short* __restrict__ Olo)
{
  const int bh = blockIdx.y;
  const int b = bh >> 4, hh = bh & 15;
  const int row = blockIdx.x*256 + threadIdx.x;
  const size_t base = ((size_t)b*TT)*DM + hh*DKH;
  float q[64];
  {
    const float* qp = Qg + base + (size_t)row*DM;
    #pragma unroll
    for (int d4=0; d4<16; d4++){
      const float4 v = *(const float4*)(qp + d4*4);
      q[d4*4+0]=v.x; q[d4*4+1]=v.y; q[d4*4+2]=v.z; q[d4*4+3]=v.w;
    }
  }
  float o[64];
  #pragma unroll
  for (int d=0;d<64;d++) o[d]=0.f;
  float m = -INFINITY, l = 0.f;
  __shared__ float Ks[64][68];
  __shared__ float Vs[64][68];
  for (int kt=0; kt<TT; kt+=64) {
    __syncthreads();
    #pragma unroll
    for (int t=0;t<4;t++){
      const int fi = threadIdx.x + t*256;
      const int j = fi>>4, dq = fi&15;
      *(float4*)&Ks[j][dq*4] = *(const float4*)(Kg + base + (size_t)(kt+j)*DM + dq*4);
      *(float4*)&Vs[j][dq*4] = *(const float4*)(Vg + base + (size_t)(kt+j)*DM + dq*4);
    }
    __syncthreads();
    for (int j=0;j<64;j++){
      float s0=0.f,s1=0.f,s2=0.f,s3=0.f;
      #pragma unroll
      for (int d=0; d<64; d+=4){
        s0 = fmaf(q[d+0], Ks[j][d+0], s0);
        s1 = fmaf(q[d+1], Ks[j][d+1], s1);
        s2 = fmaf(q[d+2], Ks[j][d+2], s2);
        s3 = fmaf(q[d+3], Ks[j][d+3], s3);
      }
      const float s = ((s0+s1)+(s2+s3)) * 0.125f;
      if (s > m) {
        const float f = __expf(m - s);
        l *= f;
        #pragma unroll
        for (int d=0;d<64;d++) o[d] *= f;
        m = s;
      }
      const float p = __expf(s - m);
      l += p;
      #pragma unroll
      for (int d=0;d<64;d++) o[d] = fmaf(p, Vs[j][d], o[d]);
    }
  }
  const float inv = 1.f / l;
  #pragma unroll
  for (int d8=0; d8<8; d8++){
    s16x8 hv, lv;
    #pragma unroll
    for (int e=0;e<8;e++){
      const float f = o[d8*8+e]*inv;
      const short hb = f2b(f);
      hv[e] = hb;
      lv[e] = f2b(f - b2f(hb));
    }
    *(s16x8*)(Ohi + base + (size_t)row*DM + d8*8) = hv;
    *(s16x8*)(Olo + base + (size_t)row*DM + d8*8) = lv;
  }
}

// encoder LayerNorm: split bf16 out
__global__ __launch_bounds__(256)
void ln_add_split(const float* __restrict__ X, const float* __restrict__ Y,
                  const float* __restrict__ g, const float* __restrict__ be,
                  short* __restrict__ Ohi, short* __restrict__ Olo)
{
  const size_t row = blockIdx.x;
  const int tid = threadIdx.x;
  const float4 a = *(const float4*)(X + row*DM + tid*4);
  const float4 b = *(const float4*)(Y + row*DM + tid*4);
  const float v0=a.x+b.x, v1=a.y+b.y, v2=a.z+b.z, v3=a.w+b.w;
  float s = v0+v1+v2+v3;
  float q = v0*v0+v1*v1+v2*v2+v3*v3;
  s = wave_sum(s); q = wave_sum(q);
  __shared__ float rs[4], rq[4];
  if ((tid&63)==0){ rs[tid>>6]=s; rq[tid>>6]=q; }
  __syncthreads();
  const float S = rs[0]+rs[1]+rs[2]+rs[3];
  const float Q = rq[0]+rq[1]+rq[2]+rq[3];
  const float mean = S * (1.f/DM);
  const float var  = Q * (1.f/DM) - mean*mean;
  const float rstd = rsqrtf(var + 1e-5f);
  const float4 gv = *(const float4*)(g  + tid*4);
  const float4 bv = *(const float4*)(be + tid*4);
  const float v[4] = {(v0-mean)*rstd*gv.x + bv.x, (v1-mean)*rstd*gv.y + bv.y,
                      (v2-mean)*rstd*gv.z + bv.z, (v3-mean)*rstd*gv.w + bv.w};
  s16x4 hv, lv;
  #pragma unroll
  for (int e=0;e<4;e++){
    const short hb = f2b(v[e]);
    hv[e] = hb;
    lv[e] = f2b(v[e] - b2f(hb));
  }
  *(s16x4*)(Ohi + row*DM + tid*4) = hv;
  *(s16x4*)(Olo + row*DM + tid*4) = lv;
}

// ================= decoder (stream-launched, fused phases) =================

__device__ inline f32x4 mfma3(const s16x8 ah, const s16x8 al,
                              const s16x8 bh, const s16x8 bl, f32x4 A){
  A = __builtin_amdgcn_mfma_f32_16x16x32_bf16(ah, bh, A, 0,0,0);
  A = __builtin_amdgcn_mfma_f32_16x16x32_bf16(ah, bl, A, 0,0,0);
  A = __builtin_amdgcn_mfma_f32_16x16x32_bf16(al, bh, A, 0,0,0);
  return A;
}

// 16-col-tile GEMM, wave-level K-split (4 waves x CHUNKS*32), direct global->reg
// fragments (no LDS in k-loop -> deep compiler pipelining). LDS cross-wave reduce.
// MODE bit0: f32 out, bit1: split out. bias nullable. mr = #16-row frags (1..6).
template<int MODE, int ACT, int CHUNKS>
__device__ inline void gemm16(const short* __restrict__ Ahi, const short* __restrict__ Alo,
    const short* __restrict__ Bhi, const short* __restrict__ Blo,
    int lda, int ldb, int ldo, int c0, int kbase, int mr,
    const float* __restrict__ bias,
    float* __restrict__ outf, short* __restrict__ ohi, short* __restrict__ olo,
    float (*red)[96][17])
{
  const int tid = threadIdx.x, lane = tid & 63, w = tid >> 6;
  const int fr = lane & 15, fq = lane >> 4;
  const size_t kw = (size_t)kbase + w*(CHUNKS*32) + fq*8;
  const short* Ah = Ahi + (size_t)fr*lda + kw;
  const short* Al = Alo + (size_t)fr*lda + kw;
  const short* Bh = Bhi + (size_t)(c0+fr)*ldb + kw;
  const short* Bl = Blo + (size_t)(c0+fr)*ldb + kw;
  f32x4 a0={0.f,0.f,0.f,0.f}, a1=a0, a2=a0, a3=a0, a4=a0, a5=a0;
  #pragma unroll
  for (int c=0; c<CHUNKS; c++){
    const int ko = c*32;
    const s16x8 bh = *(const s16x8*)(Bh + ko);
    const s16x8 bl = *(const s16x8*)(Bl + ko);
    #define AS(i, A) if (mr > i){ \
      const s16x8 ah = *(const s16x8*)(Ah + (size_t)(i*16)*lda + ko); \
      const s16x8 al = *(const s16x8*)(Al + (size_t)(i*16)*lda + ko); \
      A = mfma3(ah, al, bh, bl, A); }
    AS(0,a0) AS(1,a1) AS(2,a2) AS(3,a3) AS(4,a4) AS(5,a5)
    #undef AS
  }
  #define ST(i, A) if (mr > i){ \
    red[w][i*16+fq*4+0][fr]=A[0]; red[w][i*16+fq*4+1][fr]=A[1]; \
    red[w][i*16+fq*4+2][fr]=A[2]; red[w][i*16+fq*4+3][fr]=A[3]; }
  ST(0,a0) ST(1,a1) ST(2,a2) ST(3,a3) ST(4,a4) ST(5,a5)
  #undef ST
  __syncthreads();
  const int tot = mr*256;                  // mr*16 rows x 16 cols
  for (int o=tid; o<tot; o+=256){
    const int row = o >> 4, col = o & 15;
    float s = red[0][row][col] + red[1][row][col] + red[2][row][col] + red[3][row][col];
    if (bias) s += bias[c0 + col];
    if (ACT) s = fmaxf(s, 0.f);
    const size_t idx = (size_t)row*ldo + c0 + col;
    if (MODE & 1) outf[idx] = s;
    if (MODE & 2){
      const short hb = f2b(s);
      ohi[idx] = hb;
      olo[idx] = f2b(s - b2f(hb));
    }
  }
}

// prep: tok + PE -> split bf16, one row per block
__global__ __launch_bounds__(256)
void k_prep(short* __restrict__ Dhi, short* __restrict__ Dlo,
            const float* __restrict__ tok)
{
  const int r = blockIdx.x;
  const int i = r >> 2;
  const int d = threadIdx.x*4;
  const float4 a = *(const float4*)(tok + (size_t)r*DM + d);
  const float c1 = -9.210340371976184f / 1024.0f;
  const float e0 = expf((float)d * c1);
  const float e1 = expf((float)(d+2) * c1);
  const float a0 = (float)i * e0, a1 = (float)i * e1;
  const float v[4] = {a.x + sinf(a0), a.y + cosf(a0), a.z + sinf(a1), a.w + cosf(a1)};
  s16x4 hv, lv;
  #pragma unroll
  for (int e=0;e<4;e++){
    const short hb = f2b(v[e]);
    hv[e] = hb;
    lv[e] = f2b(v[e] - b2f(hb));
  }
  *(s16x4*)(Dhi + (size_t)r*DM + d) = hv;
  *(s16x4*)(Dlo + (size_t)r*DM + d) = lv;
}

// QKV: 192 blocks (3 mats x 64 col-tiles), f32 out + bias
__global__ __launch_bounds__(256)
void k_qkv(const short* __restrict__ Ahi, const short* __restrict__ Alo,
           const short* __restrict__ qh, const short* __restrict__ ql,
           const short* __restrict__ kh, const short* __restrict__ kl,
           const short* __restrict__ vh, const short* __restrict__ vl,
           const float* __restrict__ bq, const float* __restrict__ bk,
           const float* __restrict__ bv,
           float* __restrict__ oq, float* __restrict__ ok, float* __restrict__ ov,
           int mr)
{
  __shared__ __align__(16) float red[4][96][17];
  const int mat = blockIdx.x >> 6, t = blockIdx.x & 63;
  gemm16<1,0,8>(Ahi, Alo,
                mat==0?qh:(mat==1?kh:vh), mat==0?ql:(mat==1?kl:vl),
                DM, DM, DM, t*16, 0, mr,
                mat==0?bq:(mat==1?bk:bv),
                mat==0?oq:(mat==1?ok:ov), nullptr, nullptr, red);
}

// generic 64-block projection (K=1024)
template<int MODE>
__global__ __launch_bounds__(256)
void k_proj(const short* __restrict__ Ahi, const short* __restrict__ Alo,
            const short* __restrict__ Bh, const short* __restrict__ Bl,
            const float* __restrict__ bias,
            float* __restrict__ outf, short* __restrict__ ohi, short* __restrict__ olo,
            int mr)
{
  __shared__ __align__(16) float red[4][96][17];
  gemm16<MODE,0,8>(Ahi, Alo, Bh, Bl, DM, DM, DM, blockIdx.x*16, 0, mr,
                   bias, outf, ohi, olo, red);
}

// FFN1: 256 blocks, relu + split out
__global__ __launch_bounds__(256)
void k_ffn1(const short* __restrict__ Ahi, const short* __restrict__ Alo,
            const short* __restrict__ Bh, const short* __restrict__ Bl,
            const float* __restrict__ bias,
            short* __restrict__ ohi, short* __restrict__ olo, int mr)
{
  __shared__ __align__(16) float red[4][96][17];
  gemm16<2,1,8>(Ahi, Alo, Bh, Bl, DM, DM, DFFN, blockIdx.x*16, 0, mr,
                bias, nullptr, ohi, olo, red);
}

// FFN2: grid (64, 2): K=4096 split in two halves -> f32 partials, no bias
__global__ __launch_bounds__(256)
void k_ffn2(const short* __restrict__ Ahi, const short* __restrict__ Alo,
            const short* __restrict__ Bh, const short* __restrict__ Bl,
            float* __restrict__ part, int mr)
{
  __shared__ __align__(16) float red[4][96][17];
  gemm16<1,0,16>(Ahi, Alo, Bh, Bl, DFFN, DFFN, DM, blockIdx.x*16,
                 blockIdx.y*2048, mr,
                 nullptr, part + (size_t)blockIdx.y*PSTRIDE, nullptr, nullptr, red);
}

// self-attention (f32 Q/K/V with bias pre-added), packed rows, split out. 64 blocks.
__global__ __launch_bounds__(256)
void k_attn_self(const float* __restrict__ Qg, const float* __restrict__ Kg,
                 const float* __restrict__ Vg,
                 short* __restrict__ Ohi, short* __restrict__ Olo, int n)
{
  const int bh = blockIdx.x;
  const int b = bh >> 4, hh = bh & 15;
  const size_t base = (size_t)b*DM + hh*DKH;
  __shared__ float Qs[NSTEP][68], Ks[NSTEP][68], Vs[NSTEP][68];
  __shared__ float P[NSTEP][28];
  const int tid = threadIdx.x;
  for (int t = tid; t < 3*n*16; t += 256){
    const int tensor = t / (n*16);
    const int fi = t - tensor*(n*16);
    const int row = fi >> 4, q4 = fi & 15;
    const float* src = (tensor==0?Qg:(tensor==1?Kg:Vg)) + base + (size_t)(row*4)*DM + q4*4;
    float (*dst)[68] = (tensor==0?Qs:(tensor==1?Ks:Vs));
    *(float4*)&dst[row][q4*4] = *(const float4*)src;
  }
  __syncthreads();
  for (int idx = tid; idx < n*n; idx += 256){
    const int i = idx / n, j = idx - i*n;
    float s0=0.f,s1=0.f,s2=0.f,s3=0.f;
    #pragma unroll
    for (int d=0; d<64; d+=4){
      s0 = fmaf(Qs[i][d+0], Ks[j][d+0], s0);
      s1 = fmaf(Qs[i][d+1], Ks[j][d+1], s1);
      s2 = fmaf(Qs[i][d+2], Ks[j][d+2], s2);
      s3 = fmaf(Qs[i][d+3], Ks[j][d+3], s3);
    }
    P[i][j] = ((s0+s1)+(s2+s3))*0.125f;
  }
  __syncthreads();
  if (tid < n){
    float mm = -INFINITY;
    for (int j=0;j<n;j++) mm = fmaxf(mm, P[tid][j]);
    float l = 0.f;
    for (int j=0;j<n;j++){ const float p = __expf(P[tid][j]-mm); P[tid][j]=p; l+=p; }
    const float inv = 1.f/l;
    for (int j=0;j<n;j++) P[tid][j] *= inv;
  }
  __syncthreads();
  for (int idx = tid; idx < n*64; idx += 256){
    const int i = idx >> 6, d = idx & 63;
    float s = 0.f;
    for (int j=0;j<n;j++) s = fmaf(P[i][j], Vs[j][d], s);
    const short hb = f2b(s);
    const size_t o = base + (size_t)(i*4)*DM + d;
    Ohi[o] = hb;
    Olo[o] = f2b(s - b2f(hb));
  }
}

// cross-attn partials: grid (CSPLIT, 64); one (ks,bh) unit per block
__global__ __launch_bounds__(256)
void k_cross_part(const float* __restrict__ Qg, const short* __restrict__ Kc,
                  const short* __restrict__ Vc, float* __restrict__ opart,
                  float* __restrict__ mlpart, int n)
{
  const int ks = blockIdx.x, bh = blockIdx.y;
  const int b = bh >> 4, hh = bh & 15;
  __shared__ float Qs[NSTEP][68];
  __shared__ short KVs[CKEYS][72];
  __shared__ float S[NSTEP][132];
  const int tid = threadIdx.x;
  const size_t qbase = (size_t)b*DM + hh*DKH;
  for (int t=tid; t<n*16; t+=256){
    const int row = t>>4, q4 = t&15;
    *(float4*)&Qs[row][q4*4] = *(const float4*)(Qg + qbase + (size_t)(row*4)*DM + q4*4);
  }
  const size_t kbase = ((size_t)b*TT + (size_t)ks*CKEYS)*DM + hh*DKH;
  for (int t=tid; t<CKEYS*8; t+=256){
    const int row = t>>3, d8 = t&7;
    *(s16x8*)&KVs[row][d8*8] = *(const s16x8*)(Kc + kbase + (size_t)row*DM + d8*8);
  }
  __syncthreads();
  for (int idx=tid; idx<n*128; idx+=256){
    const int i = idx >> 7, j = idx & 127;
    float s0=0.f,s1=0.f,s2=0.f,s3=0.f;
    #pragma unroll
    for (int d=0; d<64; d+=4){
      s0 = fmaf(Qs[i][d+0], b2f(KVs[j][d+0]), s0);
      s1 = fmaf(Qs[i][d+1], b2f(KVs[j][d+1]), s1);
      s2 = fmaf(Qs[i][d+2], b2f(KVs[j][d+2]), s2);
      s3 = fmaf(Qs[i][d+3], b2f(KVs[j][d+3]), s3);
    }
    S[i][j] = ((s0+s1)+(s2+s3))*0.125f;
  }
  __syncthreads();
  for (int t=tid; t<CKEYS*8; t+=256){
    const int row = t>>3, d8 = t&7;
    *(s16x8*)&KVs[row][d8*8] = *(const s16x8*)(Vc + kbase + (size_t)row*DM + d8*8);
  }
  if (tid < n){
    float mm=-INFINITY;
    for (int j=0;j<CKEYS;j++) mm = fmaxf(mm, S[tid][j]);
    float l=0.f;
    for (int j=0;j<CKEYS;j++){ const float p=__expf(S[tid][j]-mm); S[tid][j]=p; l+=p; }
    mlpart[((size_t)bh*CSPLIT+ks)*(2*NSTEP) + tid*2+0] = mm;
    mlpart[((size_t)bh*CSPLIT+ks)*(2*NSTEP) + tid*2+1] = l;
  }
  __syncthreads();
  for (int idx=tid; idx<n*64; idx+=256){
    const int i = idx >> 6, d = idx & 63;
    float s=0.f;
    for (int j=0;j<CKEYS;j++) s = fmaf(S[i][j], b2f(KVs[j][d]), s);
    opart[(((size_t)bh*CSPLIT+ks)*NSTEP + i)*DKH + d] = s;
  }
}

// combine: 64 blocks
__global__ __launch_bounds__(256)
void k_comb(const float* __restrict__ opart, const float* __restrict__ mlp,
            short* __restrict__ Ohi, short* __restrict__ Olo, int n)
{
  const int bh = blockIdx.x;
  const int b = bh >> 4, hh = bh & 15;
  for (int idx=threadIdx.x; idx<n*64; idx+=256){
    const int i = idx >> 6, d = idx & 63;
    float M = -INFINITY;
    #pragma unroll
    for (int s=0;s<CSPLIT;s++)
      M = fmaxf(M, mlp[((size_t)bh*CSPLIT+s)*(2*NSTEP) + i*2]);
    float acc = 0.f, L = 0.f;
    #pragma unroll
    for (int s=0;s<CSPLIT;s++){
      const float mm = mlp[((size_t)bh*CSPLIT+s)*(2*NSTEP) + i*2+0];
      const float ll = mlp[((size_t)bh*CSPLIT+s)*(2*NSTEP) + i*2+1];
      const float f = __expf(mm - M);
      acc = fmaf(f, opart[(((size_t)bh*CSPLIT+s)*NSTEP + i)*DKH + d], acc);
      L   = fmaf(f, ll, L);
    }
    const float v = acc / L;
    const short hb = f2b(v);
    const size_t o = ((size_t)(i*4+b))*DM + hh*DKH + d;
    Ohi[o] = hb;
    Olo[o] = f2b(v - b2f(hb));
  }
}

// reduce FFN2 partials(2) + bias + residual -> LN -> dbuf f32 + split. rows blocks.
__global__ __launch_bounds__(256)
void k_ln(const float* __restrict__ part, const float* __restrict__ bias,
          const float* __restrict__ X, const float* __restrict__ g,
          const float* __restrict__ be,
          float* __restrict__ Outf, short* __restrict__ Ohi, short* __restrict__ Olo)
{
  const int row = blockIdx.x;
  __shared__ float rs[4], rq[4];
  const int tid = threadIdx.x;
  const float4 p0 = *(const float4*)(part + (size_t)row*DM + tid*4);
  const float4 p1 = *(const float4*)(part + PSTRIDE + (size_t)row*DM + tid*4);
  const float4 bvv = *(const float4*)(bias + tid*4);
  const float4 xv  = *(const float4*)(X + (size_t)row*DM + tid*4);
  const float v0=p0.x+p1.x+bvv.x+xv.x, v1=p0.y+p1.y+bvv.y+xv.y;
  const float v2=p0.z+p1.z+bvv.z+xv.z, v3=p0.w+p1.w+bvv.w+xv.w;
  float s = v0+v1+v2+v3;
  float q = v0*v0+v1*v1+v2*v2+v3*v3;
  s = wave_sum(s); q = wave_sum(q);
  if ((tid&63)==0){ rs[tid>>6]=s; rq[tid>>6]=q; }
  __syncthreads();
  const float S = rs[0]+rs[1]+rs[2]+rs[3];
  const float Q = rq[0]+rq[1]+rq[2]+rq[3];
  const float mean = S * (1.f/DM);
  const float var  = Q * (1.f/DM) - mean*mean;
  const float rstd = rsqrtf(var + 1e-5f);
  const float4 gv = *(const float4*)(g  + tid*4);
  const float4 bv2 = *(const float4*)(be + tid*4);
  const float v[4] = {(v0-mean)*rstd*gv.x + bv2.x, (v1-mean)*rstd*gv.y + bv2.y,
                      (v2-mean)*rstd*gv.z + bv2.z, (v3-mean)*rstd*gv.w + bv2.w};
  float4 of; of.x=v[0]; of.y=v[1]; of.z=v[2]; of.w=v[3];
  *(float4*)(Outf + (size_t)row*DM + tid*4) = of;
  s16x4 hv, lv;
  #pragma unroll
  for (int e=0;e<4;e++){
    const short hb = f2b(v[e]);
    hv[e] = hb;
    lv[e] = f2b(v[e] - b2f(hb));
  }
  *(s16x4*)(Ohi + (size_t)row*DM + tid*4) = hv;
  *(s16x4*)(Olo + (size_t)row*DM + tid*4) = lv;
}

// final projection + token embedding append: 4 blocks
__global__ __launch_bounds__(256)
void k_out(const float* __restrict__ Dv, const float* __restrict__ outW,
           const float* __restrict__ outB, const float* __restrict__ tembW,
           const float* __restrict__ tembB, float* __restrict__ dout,
           float* __restrict__ tok, int s)
{
  const int b = blockIdx.x;
  __shared__ float red[4];
  __shared__ float stepv;
  const int tid = threadIdx.x;
  const float* drow = Dv + ((size_t)(s*4 + b))*DM;
  const float4 dv4 = *(const float4*)(drow + tid*4);
  const float4 wv = *(const float4*)(outW + tid*4);
  float p = dv4.x*wv.x + dv4.y*wv.y + dv4.z*wv.z + dv4.w*wv.w;
  p = wave_sum(p);
  if ((tid&63)==0) red[tid>>6] = p;
  __syncthreads();
  if (tid==0){
    const float sv = red[0]+red[1]+red[2]+red[3] + outB[0];
    stepv = sv;
    dout[b*NSTEP + s] = sv;
  }
  __syncthreads();
  const float sv = stepv;
  if (s+1 < NSTEP){
    const int d = tid*4;
    const float4 tw = *(const float4*)(tembW + d);
    const float4 tb = *(const float4*)(tembB + d);
    float4 e;
    e.x = fmaf(sv, tw.x, tb.x); e.y = fmaf(sv, tw.y, tb.y);
    e.z = fmaf(sv, tw.z, tb.z); e.w = fmaf(sv, tw.w, tb.w);
    *(float4*)(tok + ((size_t)((s+1)*4 + b))*DM + d) = e;
  }
}

// ---------------- orchestration ----------------
extern "C" void kernel_launch(void* const* d_in, const int* in_sizes, int n_in,
                              void* d_out, int out_size, void* d_ws, size_t ws_size,
                              hipStream_t stream)
{
  (void)in_sizes; (void)n_in; (void)out_size; (void)ws_size;
  const float* x      = (const float*)d_in[0];
  const float* in_W   = (const float*)d_in[1];
  const float* in_b   = (const float*)d_in[2];
  const float* enc_Wq = (const float*)d_in[3];
  const float* enc_bq = (const float*)d_in[4];
  const float* enc_Wk = (const float*)d_in[5];
  const float* enc_bk = (const float*)d_in[6];
  const float* enc_Wv = (const float*)d_in[7];
  const float* enc_bv = (const float*)d_in[8];
  const float* enc_Wo = (const float*)d_in[9];
  const float* enc_bo = (const float*)d_in[10];
  const float* dec_Wq = (const float*)d_in[11];
  const float* dec_bq = (const float*)d_in[12];
  const float* dec_Wk = (const float*)d_in[13];
  const float* dec_bk = (const float*)d_in[14];
  const float* dec_Wv = (const float*)d_in[15];
  const float* dec_bv = (const float*)d_in[16];
  const float* dec_Wo = (const float*)d_in[17];
  const float* dec_bo = (const float*)d_in[18];
  const float* ffe_W1 = (const float*)d_in[19];
  const float* ffe_b1 = (const float*)d_in[20];
  const float* ffe_W2 = (const float*)d_in[21];
  const float* ffe_b2 = (const float*)d_in[22];
  const float* ffd_W1 = (const float*)d_in[23];
  const float* ffd_b1 = (const float*)d_in[24];
  const float* ffd_W2 = (const float*)d_in[25];
  const float* ffd_b2 = (const float*)d_in[26];
  const float* ne_g   = (const float*)d_in[27];
  const float* ne_b   = (const float*)d_in[28];
  const float* nd_g   = (const float*)d_in[29];
  const float* nd_b   = (const float*)d_in[30];
  const float* out_W  = (const float*)d_in[31];
  const float* out_b  = (const float*)d_in[32];
  const float* temb_W = (const float*)d_in[33];
  const float* temb_b = (const float*)d_in[34];
  float* dout = (float*)d_out;

  float* ws = (float*)d_ws;
  size_t off = 0;
  auto alloc  = [&](size_t n){ n = (n+3)&~(size_t)3; float* p = ws + off; off += n; return p; };
  auto allocS = [&](size_t n){ size_t nf = ((n+1)/2 + 3)&~(size_t)3; short* p = (short*)(ws + off); off += nf; return p; };

  // activations (encoder)
  short* hshi = allocS((size_t)BT*DM);
  short* hslo = allocS((size_t)BT*DM);
  float* h    = alloc((size_t)BT*DM);
  float* hn   = h;
  float* t0   = alloc((size_t)BT*DM);
  float* t1   = alloc((size_t)BT*DM);
  float* t2   = alloc((size_t)BT*DM);
  short* t3hi = allocS((size_t)BT*DM);
  short* t3lo = allocS((size_t)BT*DM);
  short* hnhi = allocS((size_t)BT*DM);
  short* hnlo = allocS((size_t)BT*DM);
  float* t4   = alloc((size_t)BT*DM);          // FFN2 out (encoder) UNION part (decoder)
  float* part = t4;
  short* fmhi = (short*)t0;
  short* fmlo = fmhi + (size_t)BT*DFFN;
  // bf16 K/V cross-attn cache
  short* kcb  = allocS((size_t)NL*BT*DM);
  short* vcb  = allocS((size_t)NL*BT*DM);
  // split inputs
  short* xshi = allocS((size_t)BT*64);
  short* xslo = allocS((size_t)BT*64);
  short* iwhi = allocS((size_t)DM*64);
  short* iwlo = allocS((size_t)DM*64);
  // per-layer reused weight slots (encoder + KV build)
  short* w0hi = allocS((size_t)DM*DM); short* w0lo = allocS((size_t)DM*DM);
  short* w1hi = allocS((size_t)DM*DM); short* w1lo = allocS((size_t)DM*DM);
  short* w2hi = allocS((size_t)DM*DM); short* w2lo = allocS((size_t)DM*DM);
  short* w3hi = allocS((size_t)DM*DM); short* w3lo = allocS((size_t)DM*DM);
  short* wfhi = allocS((size_t)DFFN*DM); short* wflo = allocS((size_t)DFFN*DM);   // ffe_W1
  short* wf2hi= allocS((size_t)DM*DFFN); short* wf2lo= allocS((size_t)DM*DFFN);   // ffe_W2
  // decoder buffers (packed rows r = i*4+b)
  float* tok  = alloc((size_t)MD*DM);
  float* dbuf = alloc((size_t)MD*DM);
  float* dq   = alloc((size_t)MD*DM);
  float* dk   = alloc((size_t)MD*DM);
  float* dv_  = alloc((size_t)MD*DM);
  short* dbhi = allocS((size_t)MD*DM);  short* dblo = allocS((size_t)MD*DM);
  short* dahi = allocS((size_t)MD*DM);  short* dalo = allocS((size_t)MD*DM);
  short* dmhi = allocS((size_t)MD*DFFN);short* dmlo = allocS((size_t)MD*DFFN);
  float* opart= alloc((size_t)BB*NH*CSPLIT*NSTEP*DKH);
  float* mlp  = alloc((size_t)BB*NH*CSPLIT*2*NSTEP);

  // decoder split weights aliased onto dead-after-encoder buffers
  const size_t MM = (size_t)DM*DM;
  short* dwq = (short*)t0;
  short* dwk = (short*)t1;
  short* dwv = (short*)t2;
  short* dwo = (short*)h;
  short* fw1h = t3hi; short* fw1l = t3lo;
  short* fw2h = hnhi; short* fw2l = hnlo;

  auto cvt = [&](const float* src, short* hi, short* lo, size_t n){
    split_kernel<<<(int)((n/8 + 255)/256), 256, 0, stream>>>(src, hi, lo, (int)(n/8));
  };

  cvt(x,    xshi, xslo, (size_t)BT*64);
  cvt(in_W, iwhi, iwlo, (size_t)DM*64);
  cvt(ffe_W1, wfhi,  wflo,  (size_t)DFFN*DM);   // layer-invariant: hoisted
  cvt(ffe_W2, wf2hi, wf2lo, (size_t)DM*DFFN);
  zero_kernel<<<(MD*DM+255)/256, 256, 0, stream>>>(tok, MD*DM);

  // input projection + PE -> split
  gemm_split<0,0><<<dim3(BT/128, DM/128), 256, 0, stream>>>(
      xshi, xslo, iwhi, iwlo, in_b, h, (short*)nullptr, (short*)nullptr, BT, DM, 64);
  add_pe_split<<<BT, 256, 0, stream>>>(h, hshi, hslo);

  // ---- encoder ----
  for (int l=0; l<NL; ++l) {
    const size_t wo = (size_t)l*DM*DM, bo_ = (size_t)l*DM;
    cvt(enc_Wq+wo, w0hi, w0lo, MM);
    cvt(enc_Wk+wo, w1hi, w1lo, MM);
    cvt(enc_Wv+wo, w2hi, w2lo, MM);
    cvt(enc_Wo+wo, w3hi, w3lo, MM);
    gemm_split<0,0><<<dim3(32,8),256,0,stream>>>(hshi, hslo, w0hi, w0lo, enc_bq+bo_,
        t0, (short*)nullptr, (short*)nullptr, BT, DM, DM);
    gemm_split<0,0><<<dim3(32,8),256,0,stream>>>(hshi, hslo, w1hi, w1lo, enc_bk+bo_,
        t1, (short*)nullptr, (short*)nullptr, BT, DM, DM);
    gemm_split<0,0><<<dim3(32,8),256,0,stream>>>(hshi, hslo, w2hi, w2lo, enc_bv+bo_,
        t2, (short*)nullptr, (short*)nullptr, BT, DM, DM);
    attn_enc<<<dim3(TT/256, BB*NH),256,0,stream>>>(t0, t1, t2, t3hi, t3lo);
    gemm_split<0,2><<<dim3(32,8),256,0,stream>>>(t3hi, t3lo, w3hi, w3lo, enc_bo+bo_,
        hn, hnhi, hnlo, BT, DM, DM);
    gemm_split<1,1><<<dim3(32,32),256,0,stream>>>(hnhi, hnlo, wfhi, wflo, ffe_b1,
        (float*)nullptr, fmhi, fmlo, BT, DFFN, DM);
    gemm_split<0,0><<<dim3(32,8),256,0,stream>>>(fmhi, fmlo, wf2hi, wf2lo, ffe_b2,
        t4, (short*)nullptr, (short*)nullptr, BT, DM, DFFN);
    ln_add_split<<<BT,256,0,stream>>>(hn, t4, ne_g, ne_b, hshi, hslo);
  }

  // ---- cross-attention K/V cache (bf16) ----
  for (int l=0; l<NL; ++l) {
    const size_t wo = (size_t)l*DM*DM, bo_ = (size_t)l*DM;
    cvt(dec_Wk+wo, w0hi, w0lo, MM);
    cvt(dec_Wv+wo, w1hi, w1lo, MM);
    gemm_split<0,3><<<dim3(32,8),256,0,stream>>>(hshi, hslo, w0hi, w0lo, dec_bk+bo_,
        (float*)nullptr, kcb+(size_t)l*BT*DM, (short*)nullptr, BT, DM, DM);
    gemm_split<0,3><<<dim3(32,8),256,0,stream>>>(hshi, hslo, w1hi, w1lo, dec_bv+bo_,
        (float*)nullptr, vcb+(size_t)l*BT*DM, (short*)nullptr, BT, DM, DM);
  }

  // ---- decoder split weights (once; into dead encoder buffers) ----
  for (int l=0; l<NL; ++l) {
    const size_t wo = (size_t)l*DM*DM;
    cvt(dec_Wq+wo, dwq + (size_t)l*2*MM, dwq + (size_t)l*2*MM + MM, MM);
    cvt(dec_Wk+wo, dwk + (size_t)l*2*MM, dwk + (size_t)l*2*MM + MM, MM);
    cvt(dec_Wv+wo, dwv + (size_t)l*2*MM, dwv + (size_t)l*2*MM + MM, MM);
    cvt(dec_Wo+wo, dwo + (size_t)l*2*MM, dwo + (size_t)l*2*MM + MM, MM);
  }
  cvt(ffd_W1, fw1h, fw1l, (size_t)DFFN*DM);
  cvt(ffd_W2, fw2h, fw2l, (size_t)DM*DFFN);

  // ---- decoder: stream-launched fused phases (10 kernels/layer) ----
  for (int s=0; s<NSTEP; ++s){
    const int n = s+1, rows = 4*n;
    const int mr = (rows + 15) >> 4;
    k_prep<<<NROW, 256, 0, stream>>>(dbhi, dblo, tok);
    for (int l=0; l<NL; ++l){
      const short* qh = dwq + (size_t)l*2*MM; const short* ql = qh + MM;
      const short* kh = dwk + (size_t)l*2*MM; const short* kl = kh + MM;
      const short* vh = dwv + (size_t)l*2*MM; const short* vl = vh + MM;
      const short* oh = dwo + (size_t)l*2*MM; const short* ol = oh + MM;
      const float* lbq = dec_bq + (size_t)l*DM;
      const float* lbk = dec_bk + (size_t)l*DM;
      const float* lbv = dec_bv + (size_t)l*DM;
      const float* lbo = dec_bo + (size_t)l*DM;
      k_qkv<<<192, 256, 0, stream>>>(dbhi, dblo, qh,ql, kh,kl, vh,vl,
          lbq, lbk, lbv, dq, dk, dv_, mr);
      k_attn_self<<<64, 256, 0, stream>>>(dq, dk, dv_, dahi, dalo, n);
      k_proj<2><<<64, 256, 0, stream>>>(dahi, dalo, oh, ol, lbo,
          (float*)nullptr, dbhi, dblo, mr);
      k_proj<1><<<64, 256, 0, stream>>>(dbhi, dblo, qh, ql, lbq,
          dq, (short*)nullptr, (short*)nullptr, mr);
      k_cross_part<<<dim3(CSPLIT, 64), 256, 0, stream>>>(dq,
          kcb + (size_t)l*BT*DM, vcb + (size_t)l*BT*DM, opart, mlp, n);
      k_comb<<<64, 256, 0, stream>>>(opart, mlp, dahi, dalo, n);
      k_proj<3><<<64, 256, 0, stream>>>(dahi, dalo, oh, ol, lbo,
          dbuf, dbhi, dblo, mr);
      k_ffn1<<<256, 256, 0, stream>>>(dbhi, dblo, fw1h, fw1l, ffd_b1,
          dmhi, dmlo, mr);
      k_ffn2<<<dim3(64,2), 256, 0, stream>>>(dmhi, dmlo, fw2h, fw2l, part, mr);
      k_ln<<<rows, 256, 0, stream>>>(part, ffd_b2, dbuf, nd_g, nd_b,
          dbuf, dbhi, dblo);
    }
    k_out<<<BB, 256, 0, stream>>>(dbuf, out_W, out_b, temb_W, temb_b, dout, tok, s);
  }
}